// Round 1
// baseline (1809.731 us; speedup 1.0000x reference)
//
#include <hip/hip_runtime.h>
#include <cstdint>
#include <cstddef>

#define B_    16
#define N_    4096
#define S_    1024
#define K_    32
#define COUT_ 128
#define NQ_   (B_*S_)

// ---------------- Kernel 1: FPS (one block per cloud) ----------------
#define FPS_T 512
#define FPS_P (N_/FPS_T)

__global__ __launch_bounds__(FPS_T) void fps_kernel(
    const float* __restrict__ pos, float* __restrict__ qpos_out,
    float* __restrict__ batch_out)
{
  __shared__ float px[N_], py[N_], pz[N_];
  __shared__ float wv[FPS_T/64];
  __shared__ int   wi[FPS_T/64];
  __shared__ int   cur;

  const int t = threadIdx.x;
  const int b = blockIdx.x;
  const int lane = t & 63;
  const int wid  = t >> 6;
  const float* pb = pos + (size_t)b * N_ * 3;

  for (int i = t; i < N_; i += FPS_T) {
    px[i] = pb[i*3+0]; py[i] = pb[i*3+1]; pz[i] = pb[i*3+2];
  }
  for (int s = t; s < S_; s += FPS_T) batch_out[(size_t)b*S_ + s] = (float)b;

  float mind[FPS_P];
  #pragma unroll
  for (int k = 0; k < FPS_P; ++k) mind[k] = INFINITY;

  __syncthreads();

  int last = 0;
  for (int s = 0; s < S_; ++s) {
    if (t < 3) {
      float v = (t==0) ? px[last] : ((t==1) ? py[last] : pz[last]);
      qpos_out[((size_t)b*S_ + s)*3 + t] = v;
    }
    if (s == S_-1) break;
    const float lx = px[last], ly = py[last], lz = pz[last];
    float bv = -1.0f; int bi = 0;
    #pragma unroll
    for (int k = 0; k < FPS_P; ++k) {
      #pragma clang fp contract(off)
      const int p = k*FPS_T + t;
      const float dx = px[p]-lx;
      const float dy = py[p]-ly;
      const float dz = pz[p]-lz;
      const float d  = dx*dx + dy*dy + dz*dz;   // exact ref order, no FMA
      const float m  = fminf(mind[k], d);
      mind[k] = m;
      if (m > bv) { bv = m; bi = p; }           // strict > keeps lowest index
    }
    // wave argmax reduce (max value, min index tiebreak = jnp.argmax)
    #pragma unroll
    for (int off = 1; off < 64; off <<= 1) {
      const float ov = __shfl_xor(bv, off);
      const int   oi = __shfl_xor(bi, off);
      if (ov > bv || (ov == bv && oi < bi)) { bv = ov; bi = oi; }
    }
    if (lane == 0) { wv[wid] = bv; wi[wid] = bi; }
    __syncthreads();
    if (t == 0) {
      float xv = wv[0]; int xi = wi[0];
      #pragma unroll
      for (int w = 1; w < FPS_T/64; ++w) {
        if (wv[w] > xv || (wv[w] == xv && wi[w] < xi)) { xv = wv[w]; xi = wi[w]; }
      }
      cur = xi;
    }
    __syncthreads();
    last = cur;
  }
}

// ---------------- Kernel 2: radius ball query (one wave per query) ----------------
__global__ __launch_bounds__(256) void radius_kernel(
    const float* __restrict__ pos, const float* __restrict__ qpos,
    int* __restrict__ nbr, int* __restrict__ cnt_out)
{
  const int lane = threadIdx.x & 63;
  const int q = blockIdx.x * 4 + (threadIdx.x >> 6);
  const int b = q >> 10;                          // q / S_
  const float* pb = pos + (size_t)b * N_ * 3;
  const float qx = qpos[(size_t)q*3+0];
  const float qy = qpos[(size_t)q*3+1];
  const float qz = qpos[(size_t)q*3+2];
  int cnt = 0;
  for (int base = 0; base < N_; base += 64) {
    #pragma clang fp contract(off)
    const int i = base + lane;
    const float dx = qx - pb[i*3+0];
    const float dy = qy - pb[i*3+1];
    const float dz = qz - pb[i*3+2];
    const float d  = dx*dx + dy*dy + dz*dz;       // exact ref order, no FMA
    const bool valid = (d <= 0.04f);              // fl(0.04) == fl(python 0.2*0.2)
    const unsigned long long bal = __ballot(valid);
    const int below = __popcll(bal & ((1ull << lane) - 1ull));
    const int p = cnt + below;
    if (valid && p < K_) nbr[(size_t)q*K_ + p] = i;
    cnt += __popcll(bal);
    if (cnt >= K_) break;                         // first-K-by-index complete
  }
  const int c = (cnt < K_) ? cnt : K_;
  if (lane >= c && lane < K_) nbr[(size_t)q*K_ + lane] = 0;  // safe gather idx
  if (lane == 0) cnt_out[q] = c;
}

// ---------------- Kernel 3: xw = x @ W1[0:64,:]  (64 rows per block) ----------------
__global__ __launch_bounds__(256) void xw_kernel(
    const float* __restrict__ x, const float* __restrict__ W1,
    float* __restrict__ xw)
{
  __shared__ float xs[64*65];   // padded rows -> conflict-free column reads
  __shared__ float ws[64*64];
  const int t = threadIdx.x;
  const size_t rowbase = (size_t)blockIdx.x * 64;
  for (int k = t; k < 4096; k += 256) {
    xs[(k >> 6)*65 + (k & 63)] = x[rowbase*64 + k];
    ws[k] = W1[k];                                // rows 0..63 of W1[67][64]
  }
  __syncthreads();
  const int rg = t >> 4, cg = t & 15;
  const int r0 = rg*4, c0 = cg*4;
  float acc[4][4] = {};
  for (int i = 0; i < 64; ++i) {
    const float4 w = *(const float4*)&ws[i*64 + c0];
    #pragma unroll
    for (int j = 0; j < 4; ++j) {
      const float a = xs[(r0+j)*65 + i];
      acc[j][0] = fmaf(a, w.x, acc[j][0]);
      acc[j][1] = fmaf(a, w.y, acc[j][1]);
      acc[j][2] = fmaf(a, w.z, acc[j][2]);
      acc[j][3] = fmaf(a, w.w, acc[j][3]);
    }
  }
  #pragma unroll
  for (int j = 0; j < 4; ++j) {
    float4 v; v.x=acc[j][0]; v.y=acc[j][1]; v.z=acc[j][2]; v.w=acc[j][3];
    *(float4*)&xw[(rowbase + r0 + j)*64 + c0] = v;
  }
}

// ---------------- Kernel 4: gather + MLP + masked max (2 queries / block) ----------------
__global__ __launch_bounds__(256) void conv_kernel(
    const float* __restrict__ pos, const float* __restrict__ qpos,
    const int* __restrict__ nbr, const int* __restrict__ cnt,
    const float* __restrict__ xw,
    const float* __restrict__ W1, const float* __restrict__ b1,
    const float* __restrict__ W2, const float* __restrict__ b2,
    const float* __restrict__ W3, const float* __restrict__ b3,
    float* __restrict__ out)
{
  __shared__ float h1s[64*68];
  __shared__ float h2s[64*68];
  __shared__ float red[8*128];
  __shared__ int   nbrs[64];
  __shared__ float qps[8];
  __shared__ int   cnts[2];

  const int t  = threadIdx.x;
  const int q0 = blockIdx.x * 2;     // even -> both queries in same cloud
  const int b  = q0 >> 10;

  if (t < 64) nbrs[t] = nbr[(size_t)q0*K_ + t];
  if (t < 2)  cnts[t] = cnt[q0 + t];
  if (t < 6)  qps[(t/3)*4 + (t%3)] = qpos[(size_t)q0*3 + t];
  __syncthreads();

  // phase 1: h1[64 rows][64] = relu(xw[nbr] + rel @ W1[64:67] + b1)
  {
    const int c = t & 63;
    const int rsub = t >> 6;
    const float w1x = W1[64*64 + c];
    const float w1y = W1[65*64 + c];
    const float w1z = W1[66*64 + c];
    const float b1v = b1[c];
    #pragma unroll
    for (int it = 0; it < 16; ++it) {
      const int row = it*4 + rsub;
      const int lq  = row >> 5;
      const int j   = nbrs[row];
      const size_t gp = (size_t)b*N_ + j;
      const float xv = xw[gp*64 + c];
      const float rx = pos[gp*3+0] - qps[lq*4+0];
      const float ry = pos[gp*3+1] - qps[lq*4+1];
      const float rz = pos[gp*3+2] - qps[lq*4+2];
      float h = fmaf(rx, w1x, xv);
      h = fmaf(ry, w1y, h);
      h = fmaf(rz, w1z, h);
      h += b1v;
      h1s[row*68 + c] = fmaxf(h, 0.0f);
    }
  }
  __syncthreads();

  // phase 2: h2[64][64] = relu(h1 @ W2 + b2), 4x4 register tiles
  {
    const int rg = t >> 4, cg = t & 15;
    const int r0 = rg*4, c0 = cg*4;
    float acc[4][4] = {};
    for (int i = 0; i < 64; i += 4) {
      float a[4][4];
      #pragma unroll
      for (int j = 0; j < 4; ++j)
        *(float4*)&a[j][0] = *(const float4*)&h1s[(r0+j)*68 + i];
      #pragma unroll
      for (int di = 0; di < 4; ++di) {
        const float4 w = *(const float4*)&W2[(i+di)*64 + c0];
        #pragma unroll
        for (int j = 0; j < 4; ++j) {
          const float av = a[j][di];
          acc[j][0] = fmaf(av, w.x, acc[j][0]);
          acc[j][1] = fmaf(av, w.y, acc[j][1]);
          acc[j][2] = fmaf(av, w.z, acc[j][2]);
          acc[j][3] = fmaf(av, w.w, acc[j][3]);
        }
      }
    }
    const float4 bb = *(const float4*)&b2[c0];
    #pragma unroll
    for (int j = 0; j < 4; ++j) {
      float4 v;
      v.x = fmaxf(acc[j][0] + bb.x, 0.0f);
      v.y = fmaxf(acc[j][1] + bb.y, 0.0f);
      v.z = fmaxf(acc[j][2] + bb.z, 0.0f);
      v.w = fmaxf(acc[j][3] + bb.w, 0.0f);
      *(float4*)&h2s[(r0+j)*68 + c0] = v;
    }
  }
  __syncthreads();

  // phase 3: h3 = h2 @ W3 (+b3 after max); masked max over neighbors
  {
    const int rg = t >> 5, cg = t & 31;
    const int r0 = rg*8, c0 = cg*4;
    const int lq = rg >> 2;
    const int cq = cnts[lq];
    float acc[8][4] = {};
    for (int i = 0; i < 64; i += 4) {
      float a[8][4];
      #pragma unroll
      for (int j = 0; j < 8; ++j)
        *(float4*)&a[j][0] = *(const float4*)&h2s[(r0+j)*68 + i];
      #pragma unroll
      for (int di = 0; di < 4; ++di) {
        const float4 w = *(const float4*)&W3[(size_t)(i+di)*128 + c0];
        #pragma unroll
        for (int j = 0; j < 8; ++j) {
          const float av = a[j][di];
          acc[j][0] = fmaf(av, w.x, acc[j][0]);
          acc[j][1] = fmaf(av, w.y, acc[j][1]);
          acc[j][2] = fmaf(av, w.z, acc[j][2]);
          acc[j][3] = fmaf(av, w.w, acc[j][3]);
        }
      }
    }
    float pm0=-INFINITY, pm1=-INFINITY, pm2=-INFINITY, pm3=-INFINITY;
    #pragma unroll
    for (int j = 0; j < 8; ++j) {
      const int n = (r0 + j) & 31;
      if (n < cq) {
        pm0 = fmaxf(pm0, acc[j][0]);
        pm1 = fmaxf(pm1, acc[j][1]);
        pm2 = fmaxf(pm2, acc[j][2]);
        pm3 = fmaxf(pm3, acc[j][3]);
      }
    }
    float4 v; v.x=pm0; v.y=pm1; v.z=pm2; v.w=pm3;
    *(float4*)&red[rg*128 + c0] = v;
  }
  __syncthreads();
  {
    const int q = t >> 7, c = t & 127;
    const int cq = cnts[q];
    float v = -INFINITY;
    #pragma unroll
    for (int j = 0; j < 4; ++j) v = fmaxf(v, red[(q*4+j)*128 + c]);
    v = (cq > 0) ? (v + b3[c]) : 0.0f;   // b3 const per column: add after max
    v = fmaxf(v, 0.0f);
    out[(size_t)(q0 + q)*COUT_ + c] = v;
  }
}

extern "C" void kernel_launch(void* const* d_in, const int* in_sizes, int n_in,
                              void* d_out, int out_size, void* d_ws, size_t ws_size,
                              hipStream_t stream) {
  const float* x   = (const float*)d_in[0];
  const float* pos = (const float*)d_in[1];
  // d_in[2] = batch (unused: equal-size clouds)
  const float* W1  = (const float*)d_in[3];
  const float* b1  = (const float*)d_in[4];
  const float* W2  = (const float*)d_in[5];
  const float* b2  = (const float*)d_in[6];
  const float* W3  = (const float*)d_in[7];
  const float* b3  = (const float*)d_in[8];

  float* out    = (float*)d_out;                       // [NQ][128]
  float* qpos   = out + (size_t)NQ_*COUT_;             // [NQ][3]
  float* batchf = qpos + (size_t)NQ_*3;                // [NQ]

  char* ws = (char*)d_ws;
  float* xw = (float*)ws;                              // [B*N][64] = 16 MB
  int* nbr  = (int*)(ws + (size_t)B_*N_*64*sizeof(float));   // [NQ][K]
  int* cnt  = nbr + (size_t)NQ_*K_;                    // [NQ]

  hipLaunchKernelGGL(xw_kernel,     dim3((B_*N_)/64), dim3(256),   0, stream, x, W1, xw);
  hipLaunchKernelGGL(fps_kernel,    dim3(B_),         dim3(FPS_T), 0, stream, pos, qpos, batchf);
  hipLaunchKernelGGL(radius_kernel, dim3(NQ_/4),      dim3(256),   0, stream, pos, qpos, nbr, cnt);
  hipLaunchKernelGGL(conv_kernel,   dim3(NQ_/2),      dim3(256),   0, stream,
                     pos, qpos, nbr, cnt, xw, W1, b1, W2, b2, W3, b3, out);
}

// Round 2
// 888.491 us; speedup vs baseline: 2.0369x; 2.0369x over previous
//
#include <hip/hip_runtime.h>
#include <cstdint>
#include <cstddef>

#define B_    16
#define N_    4096
#define S_    1024
#define K_    32
#define COUT_ 128
#define NQ_   (B_*S_)

// ---------------- Kernel 1: FPS (one block per cloud) ----------------
#define FT 256
#define FP (N_/FT)    // 16 points per thread, held in registers

// wave64 max-reduce of a u64 key via DPP (row_shr 1/2/4/8, row_bcast 15/31),
// result broadcast to all lanes via readlane(63).
__device__ __forceinline__ uint64_t wave_max_u64(uint64_t key) {
  uint32_t lo = (uint32_t)key, hi = (uint32_t)(key >> 32);
#define DPP_STEP(ctrl) { \
    uint32_t lo2 = (uint32_t)__builtin_amdgcn_update_dpp((int)lo, (int)lo, (ctrl), 0xf, 0xf, false); \
    uint32_t hi2 = (uint32_t)__builtin_amdgcn_update_dpp((int)hi, (int)hi, (ctrl), 0xf, 0xf, false); \
    const bool gt = (hi2 > hi) || (hi2 == hi && lo2 > lo); \
    hi = gt ? hi2 : hi; lo = gt ? lo2 : lo; \
  }
  DPP_STEP(0x111)  // row_shr:1
  DPP_STEP(0x112)  // row_shr:2
  DPP_STEP(0x114)  // row_shr:4
  DPP_STEP(0x118)  // row_shr:8
  DPP_STEP(0x142)  // row_bcast:15
  DPP_STEP(0x143)  // row_bcast:31
#undef DPP_STEP
  hi = (uint32_t)__builtin_amdgcn_readlane((int)hi, 63);
  lo = (uint32_t)__builtin_amdgcn_readlane((int)lo, 63);
  return ((uint64_t)hi << 32) | lo;
}

__global__ __launch_bounds__(FT) void fps_kernel(
    const float* __restrict__ pos, float* __restrict__ qpos_out,
    float* __restrict__ batch_out)
{
  __shared__ float px[N_], py[N_], pz[N_];
  __shared__ int   hist[S_];
  __shared__ uint64_t wkeys[2][FT/64];

  const int t = threadIdx.x;
  const int blk = blockIdx.x;
  const float* pb = pos + (size_t)blk * N_ * 3;

  for (int i = t; i < N_; i += FT) {
    px[i] = pb[i*3+0]; py[i] = pb[i*3+1]; pz[i] = pb[i*3+2];
  }
  for (int s = t; s < S_; s += FT) batch_out[(size_t)blk*S_ + s] = (float)blk;
  __syncthreads();

  // own coordinates in registers; mind in registers
  float rx[FP], ry[FP], rz[FP], mind[FP];
  #pragma unroll
  for (int k = 0; k < FP; ++k) {
    const int p = k*FT + t;
    rx[k] = px[p]; ry[k] = py[p]; rz[k] = pz[p];
    mind[k] = INFINITY;
  }

  int last = 0;
  for (int s = 0; s < S_; ++s) {
    if (t == 0) hist[s] = last;
    if (s == S_-1) break;
    const float lx = px[last], ly = py[last], lz = pz[last];
    uint64_t best = 0;
    #pragma unroll
    for (int k = 0; k < FP; ++k) {
      #pragma clang fp contract(off)
      const float dx = rx[k]-lx;
      const float dy = ry[k]-ly;
      const float dz = rz[k]-lz;
      const float d  = dx*dx + dy*dy + dz*dz;   // exact ref order, no FMA
      const float m  = fminf(mind[k], d);
      mind[k] = m;
      // max key == (max dist, then min point index): lo = 4095 - p
      const uint64_t key = ((uint64_t)__float_as_uint(m) << 32)
                         | (uint32_t)((N_-1) - (k*FT + t));
      if (key > best) best = key;
    }
    best = wave_max_u64(best);
    if ((t & 63) == 0) wkeys[s & 1][t >> 6] = best;
    __syncthreads();                       // single barrier per step (parity dbuf)
    uint64_t gb = wkeys[s & 1][0];
    #pragma unroll
    for (int w = 1; w < FT/64; ++w) {
      const uint64_t o = wkeys[s & 1][w];
      if (o > gb) gb = o;
    }
    last = (N_-1) - (int)(uint32_t)gb;     // every thread derives winner locally
  }
  __syncthreads();
  for (int s = t; s < S_; s += FT) {
    const int p = hist[s];
    qpos_out[((size_t)blk*S_ + s)*3 + 0] = px[p];
    qpos_out[((size_t)blk*S_ + s)*3 + 1] = py[p];
    qpos_out[((size_t)blk*S_ + s)*3 + 2] = pz[p];
  }
}

// ---------------- Kernel 2: radius ball query (one wave per query) ----------------
__global__ __launch_bounds__(256) void radius_kernel(
    const float* __restrict__ pos, const float* __restrict__ qpos,
    int* __restrict__ nbr, int* __restrict__ cnt_out)
{
  const int lane = threadIdx.x & 63;
  const int q = blockIdx.x * 4 + (threadIdx.x >> 6);
  const int b = q >> 10;                          // q / S_
  const float* pb = pos + (size_t)b * N_ * 3;
  const float qx = qpos[(size_t)q*3+0];
  const float qy = qpos[(size_t)q*3+1];
  const float qz = qpos[(size_t)q*3+2];
  int cnt = 0;
  for (int base = 0; base < N_; base += 64) {
    #pragma clang fp contract(off)
    const int i = base + lane;
    const float dx = qx - pb[i*3+0];
    const float dy = qy - pb[i*3+1];
    const float dz = qz - pb[i*3+2];
    const float d  = dx*dx + dy*dy + dz*dz;       // exact ref order, no FMA
    const bool valid = (d <= 0.04f);              // fl(0.04) == fl(python 0.2*0.2)
    const unsigned long long bal = __ballot(valid);
    const int below = __popcll(bal & ((1ull << lane) - 1ull));
    const int p = cnt + below;
    if (valid && p < K_) nbr[(size_t)q*K_ + p] = i;
    cnt += __popcll(bal);
    if (cnt >= K_) break;                         // first-K-by-index complete
  }
  const int c = (cnt < K_) ? cnt : K_;
  if (lane >= c && lane < K_) nbr[(size_t)q*K_ + lane] = 0;  // safe gather idx
  if (lane == 0) cnt_out[q] = c;
}

// ---------------- Kernel 3: xw = x @ W1[0:64,:]  (64 rows per block) ----------------
__global__ __launch_bounds__(256) void xw_kernel(
    const float* __restrict__ x, const float* __restrict__ W1,
    float* __restrict__ xw)
{
  __shared__ float xs[64*65];   // padded rows -> conflict-free column reads
  __shared__ float ws[64*64];
  const int t = threadIdx.x;
  const size_t rowbase = (size_t)blockIdx.x * 64;
  for (int k = t; k < 4096; k += 256) {
    xs[(k >> 6)*65 + (k & 63)] = x[rowbase*64 + k];
    ws[k] = W1[k];                                // rows 0..63 of W1[67][64]
  }
  __syncthreads();
  const int rg = t >> 4, cg = t & 15;
  const int r0 = rg*4, c0 = cg*4;
  float acc[4][4] = {};
  for (int i = 0; i < 64; ++i) {
    const float4 w = *(const float4*)&ws[i*64 + c0];
    #pragma unroll
    for (int j = 0; j < 4; ++j) {
      const float a = xs[(r0+j)*65 + i];
      acc[j][0] = fmaf(a, w.x, acc[j][0]);
      acc[j][1] = fmaf(a, w.y, acc[j][1]);
      acc[j][2] = fmaf(a, w.z, acc[j][2]);
      acc[j][3] = fmaf(a, w.w, acc[j][3]);
    }
  }
  #pragma unroll
  for (int j = 0; j < 4; ++j) {
    float4 v; v.x=acc[j][0]; v.y=acc[j][1]; v.z=acc[j][2]; v.w=acc[j][3];
    *(float4*)&xw[(rowbase + r0 + j)*64 + c0] = v;
  }
}

// ---------------- Kernel 4: gather + MLP + masked max (2 queries / block) ----------------
__global__ __launch_bounds__(256) void conv_kernel(
    const float* __restrict__ pos, const float* __restrict__ qpos,
    const int* __restrict__ nbr, const int* __restrict__ cnt,
    const float* __restrict__ xw,
    const float* __restrict__ W1, const float* __restrict__ b1,
    const float* __restrict__ W2, const float* __restrict__ b2,
    const float* __restrict__ W3, const float* __restrict__ b3,
    float* __restrict__ out)
{
  __shared__ float h1s[64*68];
  __shared__ float h2s[64*68];
  __shared__ float red[8*128];
  __shared__ int   nbrs[64];
  __shared__ float qps[8];
  __shared__ int   cnts[2];

  const int t  = threadIdx.x;
  const int q0 = blockIdx.x * 2;     // even -> both queries in same cloud
  const int b  = q0 >> 10;

  if (t < 64) nbrs[t] = nbr[(size_t)q0*K_ + t];
  if (t < 2)  cnts[t] = cnt[q0 + t];
  if (t < 6)  qps[(t/3)*4 + (t%3)] = qpos[(size_t)q0*3 + t];
  __syncthreads();

  // phase 1: h1[64 rows][64] = relu(xw[nbr] + rel @ W1[64:67] + b1)
  {
    const int c = t & 63;
    const int rsub = t >> 6;
    const float w1x = W1[64*64 + c];
    const float w1y = W1[65*64 + c];
    const float w1z = W1[66*64 + c];
    const float b1v = b1[c];
    #pragma unroll
    for (int it = 0; it < 16; ++it) {
      const int row = it*4 + rsub;
      const int lq  = row >> 5;
      const int j   = nbrs[row];
      const size_t gp = (size_t)b*N_ + j;
      const float xv = xw[gp*64 + c];
      const float rx = pos[gp*3+0] - qps[lq*4+0];
      const float ry = pos[gp*3+1] - qps[lq*4+1];
      const float rz = pos[gp*3+2] - qps[lq*4+2];
      float h = fmaf(rx, w1x, xv);
      h = fmaf(ry, w1y, h);
      h = fmaf(rz, w1z, h);
      h += b1v;
      h1s[row*68 + c] = fmaxf(h, 0.0f);
    }
  }
  __syncthreads();

  // phase 2: h2[64][64] = relu(h1 @ W2 + b2), 4x4 register tiles
  {
    const int rg = t >> 4, cg = t & 15;
    const int r0 = rg*4, c0 = cg*4;
    float acc[4][4] = {};
    for (int i = 0; i < 64; i += 4) {
      float a[4][4];
      #pragma unroll
      for (int j = 0; j < 4; ++j)
        *(float4*)&a[j][0] = *(const float4*)&h1s[(r0+j)*68 + i];
      #pragma unroll
      for (int di = 0; di < 4; ++di) {
        const float4 w = *(const float4*)&W2[(i+di)*64 + c0];
        #pragma unroll
        for (int j = 0; j < 4; ++j) {
          const float av = a[j][di];
          acc[j][0] = fmaf(av, w.x, acc[j][0]);
          acc[j][1] = fmaf(av, w.y, acc[j][1]);
          acc[j][2] = fmaf(av, w.z, acc[j][2]);
          acc[j][3] = fmaf(av, w.w, acc[j][3]);
        }
      }
    }
    const float4 bb = *(const float4*)&b2[c0];
    #pragma unroll
    for (int j = 0; j < 4; ++j) {
      float4 v;
      v.x = fmaxf(acc[j][0] + bb.x, 0.0f);
      v.y = fmaxf(acc[j][1] + bb.y, 0.0f);
      v.z = fmaxf(acc[j][2] + bb.z, 0.0f);
      v.w = fmaxf(acc[j][3] + bb.w, 0.0f);
      *(float4*)&h2s[(r0+j)*68 + c0] = v;
    }
  }
  __syncthreads();

  // phase 3: h3 = h2 @ W3 (+b3 after max); masked max over neighbors
  {
    const int rg = t >> 5, cg = t & 31;
    const int r0 = rg*8, c0 = cg*4;
    const int lq = rg >> 2;
    const int cq = cnts[lq];
    float acc[8][4] = {};
    for (int i = 0; i < 64; i += 4) {
      float a[8][4];
      #pragma unroll
      for (int j = 0; j < 8; ++j)
        *(float4*)&a[j][0] = *(const float4*)&h2s[(r0+j)*68 + i];
      #pragma unroll
      for (int di = 0; di < 4; ++di) {
        const float4 w = *(const float4*)&W3[(size_t)(i+di)*128 + c0];
        #pragma unroll
        for (int j = 0; j < 8; ++j) {
          const float av = a[j][di];
          acc[j][0] = fmaf(av, w.x, acc[j][0]);
          acc[j][1] = fmaf(av, w.y, acc[j][1]);
          acc[j][2] = fmaf(av, w.z, acc[j][2]);
          acc[j][3] = fmaf(av, w.w, acc[j][3]);
        }
      }
    }
    float pm0=-INFINITY, pm1=-INFINITY, pm2=-INFINITY, pm3=-INFINITY;
    #pragma unroll
    for (int j = 0; j < 8; ++j) {
      const int n = (r0 + j) & 31;
      if (n < cq) {
        pm0 = fmaxf(pm0, acc[j][0]);
        pm1 = fmaxf(pm1, acc[j][1]);
        pm2 = fmaxf(pm2, acc[j][2]);
        pm3 = fmaxf(pm3, acc[j][3]);
      }
    }
    float4 v; v.x=pm0; v.y=pm1; v.z=pm2; v.w=pm3;
    *(float4*)&red[rg*128 + c0] = v;
  }
  __syncthreads();
  {
    const int q = t >> 7, c = t & 127;
    const int cq = cnts[q];
    float v = -INFINITY;
    #pragma unroll
    for (int j = 0; j < 4; ++j) v = fmaxf(v, red[(q*4+j)*128 + c]);
    v = (cq > 0) ? (v + b3[c]) : 0.0f;   // b3 const per column: add after max
    v = fmaxf(v, 0.0f);
    out[(size_t)(q0 + q)*COUT_ + c] = v;
  }
}

extern "C" void kernel_launch(void* const* d_in, const int* in_sizes, int n_in,
                              void* d_out, int out_size, void* d_ws, size_t ws_size,
                              hipStream_t stream) {
  const float* x   = (const float*)d_in[0];
  const float* pos = (const float*)d_in[1];
  // d_in[2] = batch (unused: equal-size clouds)
  const float* W1  = (const float*)d_in[3];
  const float* b1  = (const float*)d_in[4];
  const float* W2  = (const float*)d_in[5];
  const float* b2  = (const float*)d_in[6];
  const float* W3  = (const float*)d_in[7];
  const float* b3  = (const float*)d_in[8];

  float* out    = (float*)d_out;                       // [NQ][128]
  float* qpos   = out + (size_t)NQ_*COUT_;             // [NQ][3]
  float* batchf = qpos + (size_t)NQ_*3;                // [NQ]

  char* ws = (char*)d_ws;
  float* xw = (float*)ws;                              // [B*N][64] = 16 MB
  int* nbr  = (int*)(ws + (size_t)B_*N_*64*sizeof(float));   // [NQ][K]
  int* cnt  = nbr + (size_t)NQ_*K_;                    // [NQ]

  hipLaunchKernelGGL(xw_kernel,     dim3((B_*N_)/64), dim3(256), 0, stream, x, W1, xw);
  hipLaunchKernelGGL(fps_kernel,    dim3(B_),         dim3(FT),  0, stream, pos, qpos, batchf);
  hipLaunchKernelGGL(radius_kernel, dim3(NQ_/4),      dim3(256), 0, stream, pos, qpos, nbr, cnt);
  hipLaunchKernelGGL(conv_kernel,   dim3(NQ_/2),      dim3(256), 0, stream,
                     pos, qpos, nbr, cnt, xw, W1, b1, W2, b2, W3, b3, out);
}